// Round 14
// baseline (159.215 us; speedup 1.0000x reference)
//
#include <hip/hip_runtime.h>
#include <math.h>

#define Ddim 384
#define D4 96                      // Ddim/4
#define NUM_ITEMS 16384
#define NUM_CLUSTERS 256
#define NEG_INF_F (-1e9f)
#define NTOK 4096
#define TPB 4                      // tokens per compute block (1 per wave)
#define NCB (NTOK / TPB)           // 1024 compute blocks
#define NFB 2048                   // fill blocks
#define FILL_PER_THREAD 32         // float4 stores per fill thread

__device__ __forceinline__ float dot4(const float4& a, const float4& b) {
    return a.x * b.x + a.y * b.y + a.z * b.z + a.w * b.w;
}

__device__ __forceinline__ void pin4(float4& v) {
    asm volatile("" : "+v"(v.x), "+v"(v.y), "+v"(v.z), "+v"(v.w));
}

// 3072 blocks x 256 threads (12 blocks/CU -> scheduler can load-balance;
// R11's 768x512 grid gave Occupancy=16.6%, ~1.3 waves/SIMD, latency-bound).
// bid%3==2 -> compute block (4 tokens, one per wave, end-to-end);
// else -> fill block (grid-strided zero of dummy_out).
__global__ __launch_bounds__(256, 6) void hs_fused(
    const float* __restrict__ hidden,
    const float* __restrict__ item_emb,
    const float* __restrict__ cluster_emb,
    const float* __restrict__ item_mask,
    const int*   __restrict__ targets,
    const int*   __restrict__ cluster_assign,
    const int*   __restrict__ in_cluster_id,
    float* __restrict__ dummy_out,
    float* __restrict__ ws)
{
    const int bid = blockIdx.x;
    const int tid = threadIdx.x;

    if (bid % 3 != 2) {
        // ---- fill: grid-strided plain stores; 8 MB active window/iter ----
        const int fid = (bid / 3) * 2 + (bid % 3);          // 0..2047
        float4 z; z.x = z.y = z.z = z.w = 0.f;
        float4* o4 = reinterpret_cast<float4*>(dummy_out)
                     + (size_t)fid * 256 + tid;
        #pragma unroll 8
        for (int i = 0; i < FILL_PER_THREAD; ++i)
            o4[(size_t)i * (NFB * 256)] = z;
        return;
    }

    const int cb   = bid / 3;              // 0..1023
    const int t0   = cb * TPB;
    const int lane = tid & 63;
    const int wave = tid >> 6;             // 0..3 -> token t0+wave
    const int q    = lane >> 4;            // 4-way cluster/slot subgroup
    const int r    = lane & 15;            // 16-lane D-split

    __shared__ float clog[TPB][NUM_CLUSTERS];   // 4 KB (wave-private rows)
    __shared__ float mlog[TPB][64];             // 1 KB (wave-private rows)

    const int gt   = t0 + wave;
    const int tgt  = targets[gt];
    const int tc   = cluster_assign[tgt];
    const int tpos = in_cluster_id[tgt];
    const float msk = item_mask[gt];

    const float4* h4 = reinterpret_cast<const float4*>(hidden);
    float4 hf[6];
    #pragma unroll
    for (int i = 0; i < 6; ++i) {
        hf[i] = h4[(size_t)gt * D4 + i * 16 + r];
        pin4(hf[i]);
    }

    // ---- cluster logits: 64 iters x 4 clusters, wave-solo ----
    const float4* ce4 = reinterpret_cast<const float4*>(cluster_emb);
    #pragma unroll 4
    for (int it = 0; it < 64; ++it) {
        const int c = it * 4 + q;
        float4 ce[6];
        #pragma unroll
        for (int i = 0; i < 6; ++i) ce[i] = ce4[(size_t)c * D4 + i * 16 + r];
        float u = 0.f;
        #pragma unroll
        for (int i = 0; i < 6; ++i) u += dot4(ce[i], hf[i]);
        u += __shfl_xor(u, 8);
        u += __shfl_xor(u, 4);
        u += __shfl_xor(u, 2);
        u += __shfl_xor(u, 1);
        if (r == 0) clog[wave][c] = u;
    }
    // wave-private LDS row: same-wave RAW ordered by lgkmcnt, no barrier.

    // ---- cluster softmax + argmax (first-index tiebreak) ----
    const float v0 = clog[wave][lane];
    const float v1 = clog[wave][lane + 64];
    const float v2 = clog[wave][lane + 128];
    const float v3 = clog[wave][lane + 192];
    float bv = v0; int bi = lane;
    if (v1 > bv) { bv = v1; bi = lane + 64;  }
    if (v2 > bv) { bv = v2; bi = lane + 128; }
    if (v3 > bv) { bv = v3; bi = lane + 192; }
    #pragma unroll
    for (int m = 32; m > 0; m >>= 1) {
        const float ov = __shfl_xor(bv, m);
        const int   oi = __shfl_xor(bi, m);
        if (ov > bv || (ov == bv && oi < bi)) { bv = ov; bi = oi; }
    }
    float e = expf(v0 - bv) + expf(v1 - bv) + expf(v2 - bv) + expf(v3 - bv);
    #pragma unroll
    for (int m = 32; m > 0; m >>= 1) e += __shfl_xor(e, m);
    const float lse = bv + logf(e);
    const float tlpc = clog[wave][tc] - lse;

    // ---- member: ids computed arithmetically (id = tc + 256*slot, slot<64
    // always valid; slots 64..127 are -1 -> excluded, matching the masked
    // softmax exactly). Kills the dependent crow-load in the gather chain. ----
    const float4* ie4 = reinterpret_cast<const float4*>(item_emb);
    #pragma unroll 4
    for (int it = 0; it < 16; ++it) {
        const int slot = it * 4 + q;
        const int id   = tc + (slot << 8);
        const float4* ir = ie4 + (size_t)id * D4;
        float pa = 0.f;
        #pragma unroll
        for (int i = 0; i < 6; ++i) pa += dot4(ir[i * 16 + r], hf[i]);
        pa += __shfl_xor(pa, 8);
        pa += __shfl_xor(pa, 4);
        pa += __shfl_xor(pa, 2);
        pa += __shfl_xor(pa, 1);
        if (r == 0) mlog[wave][slot] = pa;
    }
    // ---- exact 64-slot softmax ----
    const float w0 = mlog[wave][lane];
    float mx = w0;
    #pragma unroll
    for (int m = 32; m > 0; m >>= 1) mx = fmaxf(mx, __shfl_xor(mx, m));
    float e2 = expf(w0 - mx);
    #pragma unroll
    for (int m = 32; m > 0; m >>= 1) e2 += __shfl_xor(e2, m);
    const float tlpi = mlog[wave][tpos] - (mx + logf(e2));

    if (lane == 0) {
        ws[NTOK + gt]     = msk;
        ws[2 * NTOK + gt] = tlpc;
        ws[3 * NTOK + gt] = tlpi;
        ws[4 * NTOK + gt] = (bi == tc) ? 1.f : 0.f;
    }
}

// ---------- deterministic final reduction ----------
__global__ __launch_bounds__(1024) void hs_final(
    const float* __restrict__ ws, float* __restrict__ out)
{
    __shared__ double red[5][1024];
    const int tid = threadIdx.x;
    double a0 = 0, a1 = 0, a2 = 0, a3 = 0, a4 = 0;
    for (int i = tid; i < NTOK; i += 1024) {
        const float msk  = ws[NTOK + i];
        const float tlpc = ws[2 * NTOK + i];
        const float tlpi = ws[3 * NTOK + i];
        a0 += (double)(-(tlpc + tlpi) * msk);
        a1 += (double)msk;
        a2 += (double)tlpc;
        a3 += (double)tlpi;
        a4 += (double)ws[4 * NTOK + i];
    }
    red[0][tid] = a0; red[1][tid] = a1; red[2][tid] = a2;
    red[3][tid] = a3; red[4][tid] = a4;
    __syncthreads();
    for (int s2 = 512; s2 > 0; s2 >>= 1) {
        if (tid < s2) {
            red[0][tid] += red[0][tid + s2];
            red[1][tid] += red[1][tid + s2];
            red[2][tid] += red[2][tid + s2];
            red[3][tid] += red[3][tid + s2];
            red[4][tid] += red[4][tid + s2];
        }
        __syncthreads();
    }
    if (tid == 0) {
        out[0] = (float)(red[0][0] / (red[1][0] + 1e-8));
        out[1] = (float)(-red[2][0] / (double)NTOK);
        out[2] = (float)(-red[3][0] / (double)NTOK);
        out[3] = (float)(red[4][0] / (double)NTOK);
    }
}

extern "C" void kernel_launch(void* const* d_in, const int* in_sizes, int n_in,
                              void* d_out, int out_size, void* d_ws, size_t ws_size,
                              hipStream_t stream) {
    const float* hidden         = (const float*)d_in[0];
    const float* item_emb       = (const float*)d_in[1];
    const float* cluster_emb    = (const float*)d_in[2];
    const float* item_mask      = (const float*)d_in[3];
    const int*   targets        = (const int*)d_in[4];
    const int*   cluster_assign = (const int*)d_in[5];
    const int*   in_cluster_id  = (const int*)d_in[7];

    float* out = (float*)d_out;
    float* ws  = (float*)d_ws;

    const size_t dummy_elems = (size_t)NTOK * NUM_ITEMS; // 67,108,864 zeros

    hs_fused<<<NFB + NCB, 256, 0, stream>>>(
        hidden, item_emb, cluster_emb, item_mask, targets,
        cluster_assign, in_cluster_id, out, ws);
    hs_final<<<1, 1024, 0, stream>>>(ws, out + dummy_elems);
}

// Round 15
// 128.490 us; speedup vs baseline: 1.2391x; 1.2391x over previous
//
#include <hip/hip_runtime.h>
#include <math.h>

#define Ddim 384
#define D4 96                      // Ddim/4
#define NUM_ITEMS 16384
#define NUM_CLUSTERS 256
#define NEG_INF_F (-1e9f)
#define NTOK 4096
#define TPB 16                     // tokens per compute block (4 per wave)
#define NCB (NTOK / TPB)           // 256 compute blocks
#define NFB 512                    // fill blocks
#define FILL_F4 32768              // float4 per fill block
#define RSTRIDE 97                 // member-row LDS stride in float4

__device__ __forceinline__ float dot4(const float4& a, const float4& b) {
    return a.x * b.x + a.y * b.y + a.z * b.z + a.w * b.w;
}
__device__ __forceinline__ void pin4(float4& v) {
    asm volatile("" : "+v"(v.x), "+v"(v.y), "+v"(v.z), "+v"(v.w));
}

// One grid, 769 blocks x 256 threads.
//   bid == 768     -> meta (bucket tokens by target cluster)
//   bid % 3 != 2   -> fill block (grid-strided zero of dummy_out)
//   bid % 3 == 2   -> cluster block: 16 tokens, CE staged in LDS per block.
// R14 counters (2 GB reads @ ~10 TB/s, VALU 11%, occ 56%) showed the cluster
// phase re-streams the 384 KB CE table PER TOKEN and thrashes L1. Staging CE
// in LDS once per block cuts CE global traffic 1.6 GB -> 98 MB and feeds the
// dots from LDS instead of a thrashing L1.
__global__ __launch_bounds__(256, 2) void hs_mega(
    const float* __restrict__ hidden,
    const float* __restrict__ cluster_emb,
    const float* __restrict__ item_mask,
    const int*   __restrict__ targets,
    const int*   __restrict__ cluster_assign,
    float* __restrict__ dummy_out,
    float* __restrict__ ws,
    int*   __restrict__ wsI)
{
    const int bid = blockIdx.x;
    const int tid = threadIdx.x;

    __shared__ float4 ce_lds[32 * D4];          // 48 KB: chunk of 32 clusters
    __shared__ float  clog[TPB][NUM_CLUSTERS];  // 16 KB
    __shared__ int    cnt[NUM_CLUSTERS];        // meta path (3 KB)
    __shared__ int    scan[NUM_CLUSTERS];
    __shared__ int    cur[NUM_CLUSTERS];

    if (bid == NFB + NCB) {
        // ---------------- meta: bucket tokens by target cluster ----------------
        cnt[tid] = 0; cur[tid] = 0;
        __syncthreads();
        int tcv[NTOK / 256];
        #pragma unroll
        for (int i = 0; i < NTOK / 256; ++i) {
            const int t = i * 256 + tid;
            const int tc = cluster_assign[targets[t]];
            tcv[i] = tc;
            atomicAdd(&cnt[tc], 1);
        }
        __syncthreads();
        scan[tid] = cnt[tid];
        __syncthreads();
        for (int d = 1; d < 256; d <<= 1) {
            const int v = (tid >= d) ? scan[tid - d] : 0;
            __syncthreads();
            scan[tid] += v;
            __syncthreads();
        }
        wsI[tid] = scan[tid] - cnt[tid];
        if (tid == 255) wsI[256] = NTOK;
        __syncthreads();
        #pragma unroll
        for (int i = 0; i < NTOK / 256; ++i) {
            const int t = i * 256 + tid;
            const int tc = tcv[i];
            const int p = atomicAdd(&cur[tc], 1);
            wsI[257 + (scan[tc] - cnt[tc]) + p] = t;
        }
        return;
    }

    if (bid % 3 != 2) {
        // ---------------- fill: grid-strided plain float4 stores ----------------
        const int fid = (bid / 3) * 2 + (bid % 3);          // 0..511
        float4 z; z.x = z.y = z.z = z.w = 0.f;
        float4* o4 = reinterpret_cast<float4*>(dummy_out)
                     + (size_t)fid * 256 + tid;
        #pragma unroll 8
        for (int i = 0; i < FILL_F4 / 256; ++i)
            o4[(size_t)i * (NFB * 256)] = z;                // 2 MB window/iter
        return;
    }

    // ---------------- cluster block: 16 tokens, CE from LDS ----------------
    const int cb   = bid / 3;             // 0..255
    const int t0   = cb * TPB;
    const int lane = tid & 63;
    const int wid  = tid >> 6;            // 0..3
    const int q    = lane >> 4;           // 4-cluster subgroup
    const int r    = lane & 15;           // 16-lane D-split

    const int tw = t0 + wid * 4;
    const float4* h4 = reinterpret_cast<const float4*>(hidden);
    float4 hf[4][6];
    #pragma unroll
    for (int j = 0; j < 4; ++j)
        #pragma unroll
        for (int i = 0; i < 6; ++i) {
            hf[j][i] = h4[(size_t)(tw + j) * D4 + i * 16 + r];
            pin4(hf[j][i]);
        }

    const float4* ce4 = reinterpret_cast<const float4*>(cluster_emb);
    for (int ch = 0; ch < 8; ++ch) {
        __syncthreads();
        // stage chunk: contiguous 3072 float4s -> perfectly coalesced
        #pragma unroll
        for (int jj = 0; jj < 12; ++jj)
            ce_lds[jj * 256 + tid] = ce4[ch * 3072 + jj * 256 + tid];
        __syncthreads();

        #pragma unroll 2
        for (int it = 0; it < 8; ++it) {
            const int cl = it * 4 + q;                  // 0..31 within chunk
            float4 ce[6];
            #pragma unroll
            for (int i = 0; i < 6; ++i) ce[i] = ce_lds[cl * D4 + i * 16 + r];
            float a0 = 0.f, a1 = 0.f, a2 = 0.f, a3 = 0.f;
            #pragma unroll
            for (int i = 0; i < 6; ++i) {
                a0 += dot4(ce[i], hf[0][i]);
                a1 += dot4(ce[i], hf[1][i]);
                a2 += dot4(ce[i], hf[2][i]);
                a3 += dot4(ce[i], hf[3][i]);
            }
            // fold 4 accumulators over 16 lanes: 5 shuffles total
            const bool hi8 = (r & 8) != 0;
            float u  = hi8 ? a1 : a0;
            float uS = hi8 ? a0 : a1;
            u += __shfl_xor(uS, 8);
            float w  = hi8 ? a3 : a2;
            float wS = hi8 ? a2 : a3;
            w += __shfl_xor(wS, 8);
            const bool hi4 = (r & 4) != 0;
            float zv = hi4 ? w : u;
            float zS = hi4 ? u : w;
            zv += __shfl_xor(zS, 4);
            zv += __shfl_xor(zv, 2);
            zv += __shfl_xor(zv, 1);
            if ((r & 3) == 0) {
                const int m = (r >> 2) & 3;             // class -> token {0,2,1,3}
                const int tokj = (m == 1) ? 2 : (m == 2) ? 1 : m;
                clog[wid * 4 + tokj][ch * 32 + cl] = zv;
            }
        }
    }
    __syncthreads();

    // ---- wave-local softmax + argmax (first-index tiebreak), 4 tokens/wave ----
    #pragma unroll
    for (int p = 0; p < 4; ++p) {
        const int t  = wid * 4 + p;
        const int gt = t0 + t;
        const float v0 = clog[t][lane];
        const float v1 = clog[t][lane + 64];
        const float v2 = clog[t][lane + 128];
        const float v3 = clog[t][lane + 192];
        float bv = v0; int bi = lane;
        if (v1 > bv) { bv = v1; bi = lane + 64;  }
        if (v2 > bv) { bv = v2; bi = lane + 128; }
        if (v3 > bv) { bv = v3; bi = lane + 192; }
        #pragma unroll
        for (int m = 32; m > 0; m >>= 1) {
            const float ov = __shfl_xor(bv, m);
            const int   oi = __shfl_xor(bi, m);
            if (ov > bv || (ov == bv && oi < bi)) { bv = ov; bi = oi; }
        }
        float e = expf(v0 - bv) + expf(v1 - bv) + expf(v2 - bv) + expf(v3 - bv);
        #pragma unroll
        for (int m = 32; m > 0; m >>= 1) e += __shfl_xor(e, m);
        const float lse = bv + logf(e);
        if (lane == 0) {
            const int tc = cluster_assign[targets[gt]];
            ws[NTOK + gt]     = item_mask[gt];
            ws[2 * NTOK + gt] = clog[t][tc] - lse;
            ws[4 * NTOK + gt] = (bi == tc) ? 1.f : 0.f;
        }
    }
}

// ---------- member logits, bucketed by cluster (256 blocks) ----------
// item_emb is read ~once total (24 MB) instead of per-token (400 MB).
// Member ids are arithmetic: cluster c slots are id = c + 256*s, s < 64
// (slots 64..127 are -1 / masked out in the reference).
__global__ __launch_bounds__(256) void hs_member(
    const float* __restrict__ hidden,
    const float* __restrict__ item_emb,
    const int*   __restrict__ targets,
    const int*   __restrict__ in_cluster_id,
    const int*   __restrict__ wsI,
    float* __restrict__ ws)
{
    const int c    = blockIdx.x;
    const int tid  = threadIdx.x;
    const int lane = tid & 63;
    const int wid  = tid >> 6;

    __shared__ float4 rows[64 * RSTRIDE];   // 99.3 KB, XOR-swizzled

    const int off  = wsI[c];
    const int cntc = wsI[c + 1] - off;
    if (cntc == 0) return;

    const float4* ie4 = reinterpret_cast<const float4*>(item_emb);
    for (int j = tid; j < 64 * D4; j += 256) {
        const int s = j / D4, col = j % D4;
        const int id = c + (s << 8);
        rows[s * RSTRIDE + (col ^ ((s >> 3) & 7))] = ie4[(size_t)id * D4 + col];
    }
    __syncthreads();

    const int  swz  = (lane >> 3) & 7;
    const int* list = wsI + 257;

    for (int i = wid * 2; i < cntc; i += 8) {
        const int tokA  = __builtin_amdgcn_readfirstlane(list[off + i]);
        const bool hasB = (i + 1) < cntc;
        const int tokB  = hasB ? __builtin_amdgcn_readfirstlane(list[off + i + 1]) : tokA;
        const float4* hA = reinterpret_cast<const float4*>(hidden + (size_t)tokA * Ddim);
        const float4* hB = reinterpret_cast<const float4*>(hidden + (size_t)tokB * Ddim);
        float mA = 0.f, mB = 0.f;
        #pragma unroll 8
        for (int k = 0; k < D4; ++k) {
            const float4 rv = rows[lane * RSTRIDE + (k ^ swz)];
            mA += dot4(rv, hA[k]);          // hA[k] uniform -> scalar load
            mB += dot4(rv, hB[k]);
        }
        float mxA = mA, mxB = mB;
        #pragma unroll
        for (int m = 32; m > 0; m >>= 1) {
            mxA = fmaxf(mxA, __shfl_xor(mxA, m));
            mxB = fmaxf(mxB, __shfl_xor(mxB, m));
        }
        float eA = expf(mA - mxA);
        float eB = expf(mB - mxB);
        #pragma unroll
        for (int m = 32; m > 0; m >>= 1) {
            eA += __shfl_xor(eA, m);
            eB += __shfl_xor(eB, m);
        }
        const int tpA = in_cluster_id[targets[tokA]];
        const int tpB = in_cluster_id[targets[tokB]];
        const float vA = __shfl(mA, tpA);
        const float vB = __shfl(mB, tpB);
        if (lane == 0) {
            ws[3 * NTOK + tokA] = vA - (mxA + logf(eA));
            if (hasB) ws[3 * NTOK + tokB] = vB - (mxB + logf(eB));
        }
    }
}

// ---------- deterministic final reduction ----------
__global__ __launch_bounds__(1024) void hs_final(
    const float* __restrict__ ws, float* __restrict__ out)
{
    __shared__ double red[5][1024];
    const int tid = threadIdx.x;
    double a0 = 0, a1 = 0, a2 = 0, a3 = 0, a4 = 0;
    for (int i = tid; i < NTOK; i += 1024) {
        const float msk  = ws[NTOK + i];
        const float tlpc = ws[2 * NTOK + i];
        const float tlpi = ws[3 * NTOK + i];
        a0 += (double)(-(tlpc + tlpi) * msk);
        a1 += (double)msk;
        a2 += (double)tlpc;
        a3 += (double)tlpi;
        a4 += (double)ws[4 * NTOK + i];
    }
    red[0][tid] = a0; red[1][tid] = a1; red[2][tid] = a2;
    red[3][tid] = a3; red[4][tid] = a4;
    __syncthreads();
    for (int s2 = 512; s2 > 0; s2 >>= 1) {
        if (tid < s2) {
            red[0][tid] += red[0][tid + s2];
            red[1][tid] += red[1][tid + s2];
            red[2][tid] += red[2][tid + s2];
            red[3][tid] += red[3][tid + s2];
            red[4][tid] += red[4][tid + s2];
        }
        __syncthreads();
    }
    if (tid == 0) {
        out[0] = (float)(red[0][0] / (red[1][0] + 1e-8));
        out[1] = (float)(-red[2][0] / (double)NTOK);
        out[2] = (float)(-red[3][0] / (double)NTOK);
        out[3] = (float)(red[4][0] / (double)NTOK);
    }
}

extern "C" void kernel_launch(void* const* d_in, const int* in_sizes, int n_in,
                              void* d_out, int out_size, void* d_ws, size_t ws_size,
                              hipStream_t stream) {
    const float* hidden         = (const float*)d_in[0];
    const float* item_emb       = (const float*)d_in[1];
    const float* cluster_emb    = (const float*)d_in[2];
    const float* item_mask      = (const float*)d_in[3];
    const int*   targets        = (const int*)d_in[4];
    const int*   cluster_assign = (const int*)d_in[5];
    const int*   in_cluster_id  = (const int*)d_in[7];

    float* out = (float*)d_out;
    float* ws  = (float*)d_ws;
    int*   wsI = (int*)(ws + 5 * NTOK);

    const size_t dummy_elems = (size_t)NTOK * NUM_ITEMS; // 67,108,864 zeros

    hs_mega<<<NFB + NCB + 1, 256, 0, stream>>>(
        hidden, cluster_emb, item_mask, targets, cluster_assign, out, ws, wsI);
    hs_member<<<NUM_CLUSTERS, 256, 0, stream>>>(
        hidden, item_emb, targets, in_cluster_id, wsI, ws);
    hs_final<<<1, 1024, 0, stream>>>(ws, out + dummy_elems);
}

// Round 16
// 124.073 us; speedup vs baseline: 1.2832x; 1.0356x over previous
//
#include <hip/hip_runtime.h>
#include <math.h>

#define Ddim 384
#define D4 96                      // Ddim/4
#define NUM_ITEMS 16384
#define NUM_CLUSTERS 256
#define MCS 128                    // MAX_CLUSTER_SIZE
#define NEG_INF_F (-1e9f)
#define NTOK 4096
#define TPB 16                     // tokens per compute block
#define NCB (NTOK / TPB)           // 256 compute blocks
#define NFB 512                    // fill blocks

typedef float vf4 __attribute__((ext_vector_type(4)));

__device__ __forceinline__ float dot4(const float4& a, const float4& b) {
    return a.x * b.x + a.y * b.y + a.z * b.z + a.w * b.w;
}

// Streaming zero-store: system scope + non-temporal -> no L2/L3 write-allocate,
// straight to memory. Tests whether the ~2.3 TB/s fill ceiling observed across
// R4-R15 is cache write-allocate pollution (vs a hard path limit).
__device__ __forceinline__ void store_stream_zero(vf4* p) {
    vf4 z = (vf4)0.f;
    asm volatile("global_store_dwordx4 %0, %1, off sc0 sc1 nt"
                 :: "v"(p), "v"(z) : "memory");
}

// One grid, 768 blocks x 512 threads (R11 structure verbatim otherwise).
// bid%3!=2 -> fill; bid%3==2 -> compute (16 tokens, 8 waves: cluster via
// 4 token-quads x 2 cluster-halves, then each wave finishes 2 tokens with
// direct member gather, arithmetic slot ids implicit via cluster_idx rows).
__global__ __launch_bounds__(512, 2) void hs_fused(
    const float* __restrict__ hidden,
    const float* __restrict__ item_emb,
    const float* __restrict__ cluster_emb,
    const float* __restrict__ item_mask,
    const int*   __restrict__ targets,
    const int*   __restrict__ cluster_assign,
    const int*   __restrict__ cluster_idx,
    const int*   __restrict__ in_cluster_id,
    float* __restrict__ dummy_out,
    float* __restrict__ ws)
{
    const int bid = blockIdx.x;
    const int tid = threadIdx.x;

    if (bid % 3 != 2) {
        // ---- fill: 512 KB per block, streaming stores (sc0 sc1 nt) ----
        const int fid = (bid / 3) * 2 + (bid % 3);          // 0..511
        vf4* o4 = reinterpret_cast<vf4*>(dummy_out)
                  + (size_t)fid * 512 + tid;
        #pragma unroll 8
        for (int i = 0; i < 64; ++i)
            store_stream_zero(o4 + (size_t)i * (NFB * 512)); // 4 MB window/iter
        return;
    }

    const int cb    = bid / 3;             // 0..255
    const int t0    = cb * TPB;
    const int lane  = tid & 63;
    const int wave  = tid >> 6;            // 0..7
    const int whalf = wave >> 2;           // cluster half
    const int wq    = wave & 3;            // token quad
    const int q     = lane >> 4;           // cluster subgroup 0..3
    const int r     = lane & 15;           // 16-lane D-split

    __shared__ float clog[TPB][NUM_CLUSTERS];   // 16 KB
    __shared__ float mlog[TPB][64];             // 4 KB

    // ---- cluster logits: wave covers 128 clusters x 4 tokens ----
    const int tw = t0 + wq * 4;
    const float4* h4 = reinterpret_cast<const float4*>(hidden);
    float4 hf[4][6];
    #pragma unroll
    for (int j = 0; j < 4; ++j)
        #pragma unroll
        for (int i = 0; i < 6; ++i)
            hf[j][i] = h4[(size_t)(tw + j) * D4 + i * 16 + r];

    const float4* ce4 = reinterpret_cast<const float4*>(cluster_emb);
    #pragma unroll 2
    for (int it = 0; it < 32; ++it) {
        const int c = whalf * 128 + it * 4 + q;
        float4 ce[6];
        #pragma unroll
        for (int i = 0; i < 6; ++i) ce[i] = ce4[(size_t)c * D4 + i * 16 + r];
        float a0 = 0.f, a1 = 0.f, a2 = 0.f, a3 = 0.f;
        #pragma unroll
        for (int i = 0; i < 6; ++i) {
            a0 += dot4(ce[i], hf[0][i]);
            a1 += dot4(ce[i], hf[1][i]);
            a2 += dot4(ce[i], hf[2][i]);
            a3 += dot4(ce[i], hf[3][i]);
        }
        // fold 4 accumulators over 16 lanes: 5 shuffles total
        const bool hi8 = (r & 8) != 0;
        float u  = hi8 ? a1 : a0;
        float uS = hi8 ? a0 : a1;
        u += __shfl_xor(uS, 8);
        float w  = hi8 ? a3 : a2;
        float wS = hi8 ? a2 : a3;
        w += __shfl_xor(wS, 8);
        const bool hi4 = (r & 4) != 0;
        float zv = hi4 ? w : u;
        float zS = hi4 ? u : w;
        zv += __shfl_xor(zS, 4);
        zv += __shfl_xor(zv, 2);
        zv += __shfl_xor(zv, 1);
        if ((r & 3) == 0) {
            const int m = (r >> 2) & 3;               // class -> token {0,2,1,3}
            const int tokj = (m == 1) ? 2 : (m == 2) ? 1 : m;
            clog[wq * 4 + tokj][c] = zv;
        }
    }
    __syncthreads();   // two waves fill each token's clog row

    // ---- per wave: finish 2 tokens (softmax + member) ----
    const int r8 = lane & 7;
    const int g8 = lane >> 3;
    const float4* ie4 = reinterpret_cast<const float4*>(item_emb);

    #pragma unroll
    for (int p = 0; p < 2; ++p) {
        const int t  = wave * 2 + p;
        const int gt = t0 + t;
        const int tgt  = targets[gt];
        const int tc   = cluster_assign[tgt];
        const int tpos = in_cluster_id[tgt];
        const float msk = item_mask[gt];

        // cluster softmax + argmax (first-index tiebreak)
        const float v0 = clog[t][lane];
        const float v1 = clog[t][lane + 64];
        const float v2 = clog[t][lane + 128];
        const float v3 = clog[t][lane + 192];
        float bv = v0; int bi = lane;
        if (v1 > bv) { bv = v1; bi = lane + 64;  }
        if (v2 > bv) { bv = v2; bi = lane + 128; }
        if (v3 > bv) { bv = v3; bi = lane + 192; }
        #pragma unroll
        for (int m = 32; m > 0; m >>= 1) {
            const float ov = __shfl_xor(bv, m);
            const int   oi = __shfl_xor(bi, m);
            if (ov > bv || (ov == bv && oi < bi)) { bv = ov; bi = oi; }
        }
        float e = expf(v0 - bv) + expf(v1 - bv) + expf(v2 - bv) + expf(v3 - bv);
        #pragma unroll
        for (int m = 32; m > 0; m >>= 1) e += __shfl_xor(e, m);
        const float lse = bv + logf(e);
        const float tlpc = clog[t][tc] - lse;

        // ---- member: 8-lane groups, 8 rows in flight, 64 valid slots ----
        float4 hme[12];
        #pragma unroll
        for (int i = 0; i < 12; ++i)
            hme[i] = h4[(size_t)gt * D4 + i * 8 + r8];
        const int* crow = cluster_idx + (size_t)tc * MCS;
        #pragma unroll 2
        for (int it = 0; it < 8; ++it) {
            const int id = crow[it * 8 + g8];   // always >= 0 for slot < 64
            const float4* ir = ie4 + (size_t)id * D4;
            float pa = 0.f;
            #pragma unroll
            for (int i = 0; i < 12; ++i) pa += dot4(ir[i * 8 + r8], hme[i]);
            pa += __shfl_xor(pa, 1);
            pa += __shfl_xor(pa, 2);
            pa += __shfl_xor(pa, 4);
            if (r8 == 0) mlog[t][it * 8 + g8] = pa;
        }
        // wave-local softmax over 64 slots (exact: slots 64..127 are masked)
        const float w0 = mlog[t][lane];
        float mx = w0;
        #pragma unroll
        for (int m = 32; m > 0; m >>= 1) mx = fmaxf(mx, __shfl_xor(mx, m));
        float e2 = expf(w0 - mx);
        #pragma unroll
        for (int m = 32; m > 0; m >>= 1) e2 += __shfl_xor(e2, m);
        const float tlpi = mlog[t][tpos] - (mx + logf(e2));

        if (lane == 0) {
            ws[NTOK + gt]     = msk;
            ws[2 * NTOK + gt] = tlpc;
            ws[3 * NTOK + gt] = tlpi;
            ws[4 * NTOK + gt] = (bi == tc) ? 1.f : 0.f;
        }
    }
}

// ---------- deterministic final reduction ----------
__global__ __launch_bounds__(1024) void hs_final(
    const float* __restrict__ ws, float* __restrict__ out)
{
    __shared__ double red[5][1024];
    const int tid = threadIdx.x;
    double a0 = 0, a1 = 0, a2 = 0, a3 = 0, a4 = 0;
    for (int i = tid; i < NTOK; i += 1024) {
        const float msk  = ws[NTOK + i];
        const float tlpc = ws[2 * NTOK + i];
        const float tlpi = ws[3 * NTOK + i];
        a0 += (double)(-(tlpc + tlpi) * msk);
        a1 += (double)msk;
        a2 += (double)tlpc;
        a3 += (double)tlpi;
        a4 += (double)ws[4 * NTOK + i];
    }
    red[0][tid] = a0; red[1][tid] = a1; red[2][tid] = a2;
    red[3][tid] = a3; red[4][tid] = a4;
    __syncthreads();
    for (int s2 = 512; s2 > 0; s2 >>= 1) {
        if (tid < s2) {
            red[0][tid] += red[0][tid + s2];
            red[1][tid] += red[1][tid + s2];
            red[2][tid] += red[2][tid + s2];
            red[3][tid] += red[3][tid + s2];
            red[4][tid] += red[4][tid + s2];
        }
        __syncthreads();
    }
    if (tid == 0) {
        out[0] = (float)(red[0][0] / (red[1][0] + 1e-8));
        out[1] = (float)(-red[2][0] / (double)NTOK);
        out[2] = (float)(-red[3][0] / (double)NTOK);
        out[3] = (float)(red[4][0] / (double)NTOK);
    }
}

extern "C" void kernel_launch(void* const* d_in, const int* in_sizes, int n_in,
                              void* d_out, int out_size, void* d_ws, size_t ws_size,
                              hipStream_t stream) {
    const float* hidden         = (const float*)d_in[0];
    const float* item_emb       = (const float*)d_in[1];
    const float* cluster_emb    = (const float*)d_in[2];
    const float* item_mask      = (const float*)d_in[3];
    const int*   targets        = (const int*)d_in[4];
    const int*   cluster_assign = (const int*)d_in[5];
    const int*   cluster_idx    = (const int*)d_in[6];
    const int*   in_cluster_id  = (const int*)d_in[7];

    float* out = (float*)d_out;
    float* ws  = (float*)d_ws;

    const size_t dummy_elems = (size_t)NTOK * NUM_ITEMS; // 67,108,864 zeros

    hs_fused<<<NFB + NCB, 512, 0, stream>>>(
        hidden, item_emb, cluster_emb, item_mask, targets,
        cluster_assign, cluster_idx, in_cluster_id, out, ws);
    hs_final<<<1, 1024, 0, stream>>>(ws, out + dummy_elems);
}